// Round 4
// baseline (271.101 us; speedup 1.0000x reference)
//
#include <hip/hip_runtime.h>

// ---------------------------------------------------------------------------
// MultiheadSelfAttention (row-local head-mixing variant), MI355X / gfx950.
// Round 12: 8-phase GEMM1 attempt #3 -- phase-ahead ds_reads.  R11 measured
// conflicts=0 but util 39%/block: ds_reads issued pre-barrier were consumed
// right after it (lgkm0 -> full LDS latency serialized before each MFMA
// cluster).  Now phase p issues the reads phase p+1 consumes; waits become
// counted lgkm(4)/(8) (operands got a full phase of latency); vmcnt(4)/(2)
// guards before next-tile LDS reads.  b01 double-buffered by tile parity
// (compile-time).  GEMM2 reverted to plain launch_bounds(256) (R8 config).
// ---------------------------------------------------------------------------

typedef __bf16 bf16x8 __attribute__((ext_vector_type(8)));
typedef float  f32x16 __attribute__((ext_vector_type(16)));
typedef float  f32x4  __attribute__((ext_vector_type(4)));

typedef __attribute__((address_space(3))) void       lds_void;
typedef const __attribute__((address_space(1))) void gbl_void;

__device__ __forceinline__ unsigned short f2b(float f) {
    unsigned int u = __builtin_bit_cast(unsigned int, f);
    return (unsigned short)((u + 0x7FFFu + ((u >> 16) & 1u)) >> 16);  // RNE
}
__device__ __forceinline__ unsigned int pack2(float a, float b) {
    return (unsigned int)f2b(a) | ((unsigned int)f2b(b) << 16);
}
__device__ __forceinline__ void unpack8(uint4 u, float* f) {
    unsigned int w[4] = {u.x, u.y, u.z, u.w};
#pragma unroll
    for (int a = 0; a < 4; ++a) {
        union { unsigned int i; float f; } lo, hi;
        lo.i = w[a] << 16;
        hi.i = w[a] & 0xFFFF0000u;
        f[a * 2]     = lo.f;
        f[a * 2 + 1] = hi.f;
    }
}

// ------------------------- fused fp32 -> bf16 cast -------------------------
__global__ __launch_bounds__(256) void cvt_all(const float* __restrict__ x,
                                               const float* __restrict__ wqkv,
                                               const float* __restrict__ wproj,
                                               unsigned short* __restrict__ xb,
                                               unsigned short* __restrict__ wqkvb,
                                               unsigned short* __restrict__ wprojb) {
    int i = blockIdx.x * 256 + threadIdx.x;
    const float* src;
    unsigned short* dst;
    if (i < 2097152)      { src = x;     dst = xb;                   }
    else if (i < 2883584) { src = wqkv;  dst = wqkvb;  i -= 2097152; }
    else                  { src = wproj; dst = wprojb; i -= 2883584; }
    float4 f = reinterpret_cast<const float4*>(src)[i];
    ushort4 u;
    u.x = f2b(f.x); u.y = f2b(f.y); u.z = f2b(f.z); u.w = f2b(f.w);
    reinterpret_cast<ushort4*>(dst)[i] = u;
}

__device__ __forceinline__ void store_c(float* C, long idx, float v)          { C[idx] = v; }
__device__ __forceinline__ void store_c(unsigned short* C, long idx, float v) { C[idx] = f2b(v); }

// ------------- 256x256 8-phase pipelined bf16 NT GEMM (Round 12) -----------
// C[m,n] = sum_k A[m,k]*B[n,k].  512 thr = 8 waves (2M x 4N); wave tile
// 128x64 = acc[8][4] of 16x16x32.  LDS 2x(A 256x64 + B 256x64) = 128 KiB.
// Chunk c of row r at slot c^(r&7); linear gload_lds dest + inverse-swizzled
// global source; 16x16 reads are 2-way residual = free, conflicts = 0 (R11).
// Quadrants per K-tile: q00(af_lo,b01) q01(af_lo,b23) q11(af_hi,b23)
// q10(af_hi,b01).  Reads issued ONE PHASE AHEAD of their MFMA consumer:
//   ph1: RB23   (ph2's B)      ph2: RA_hi  (ph3's A)
//   ph3: RB01'  (next tile)    ph4: RA_lo' (next tile)
// lgkm(4)/(8) alternating leaves exactly the current phase's reads pending.
// Staging (1 half-tile/phase, R11-verified lifetimes):
//   ph1/2: A(u+1)h0/h1  ph3/4: B(u+2)h0/h1  ph5/6: A(u+2)h0/h1  ph7/8: B(u+3)
// vmcnt guards before next-tile LDS reads: ph3/ph7: vmcnt(4); ph4/ph8: vmcnt(2).
#define BAR    __builtin_amdgcn_s_barrier()
#define LGK(n) asm volatile("s_waitcnt lgkmcnt(" #n ")" ::: "memory")
#define VMC(n) asm volatile("s_waitcnt vmcnt(" #n ")" ::: "memory")

template <typename CT>
__global__ __launch_bounds__(512, 2) void gemm256pp(const unsigned short* __restrict__ A,
                                                    const unsigned short* __restrict__ B,
                                                    CT* __restrict__ C,
                                                    int M, int N, int K, int NBX) {
    __shared__ __align__(16) unsigned short sA[2][16384];  // 2 x 32 KiB
    __shared__ __align__(16) unsigned short sB[2][16384];  // 2 x 32 KiB

    const int tid  = threadIdx.x;
    const int lane = tid & 63;
    const int wave = tid >> 6;
    const int wm   = wave >> 2;            // 0..1  (M half)
    const int wn   = wave & 3;             // 0..3  (N quarter)

    // bijective XCD swizzle (gridDim.x % 8 == 0)
    const int nwg = gridDim.x;
    const int cpx = nwg >> 3;
    const int swz = (blockIdx.x & 7) * cpx + (blockIdx.x >> 3);
    const long bm = swz / NBX;
    const long bn = swz % NBX;

    const unsigned short* Ab = A + bm * 256 * (long)K;
    const unsigned short* Bb = B + bn * 256 * (long)K;

    f32x4 acc[8][4] = {};

    auto stage = [&](const unsigned short* __restrict__ G, unsigned short* L,
                     int tile, int half) {
        const int r = tid >> 3;                            // 0..63
        const int c = ((tid & 7) ^ (r & 7)) << 3;
        const unsigned short* g = G + (long)(half * 128 + r) * K + (long)tile * 64 + c;
        unsigned short* l = L + half * 8192 + wave * 512;
#pragma unroll
        for (int j = 0; j < 2; ++j)
            __builtin_amdgcn_global_load_lds((gbl_void*)(g + (long)j * 64 * K),
                                             (lds_void*)(l + j * 4096), 16, 0, 0);
    };

    const int fr = lane & 15;              // fragment row (A) / col (B)
    const int fk = lane >> 4;              // k-chunk 0..3
    const int sx = lane & 7;               // swizzle XOR (row&7 == lane&7)

    bf16x8 af_lo[4][2], af_hi[4][2], b01[2][2][2], b23[2][2];

    auto rdA = [&](bf16x8 (&dst)[4][2], int q, int mbase) {
#pragma unroll
        for (int mt = 0; mt < 4; ++mt) {
            const int row = wm * 128 + (mbase + mt) * 16 + fr;
#pragma unroll
            for (int h = 0; h < 2; ++h)
                dst[mt][h] = *reinterpret_cast<const bf16x8*>(
                    &sA[q][row * 64 + (((h * 4 + fk) ^ sx) << 3)]);
        }
    };
    auto rdB = [&](bf16x8 (&dst)[2][2], int q, int nbase) {
#pragma unroll
        for (int nt = 0; nt < 2; ++nt) {
            const int row = wn * 64 + (nbase + nt) * 16 + fr;
#pragma unroll
            for (int h = 0; h < 2; ++h)
                dst[nt][h] = *reinterpret_cast<const bf16x8*>(
                    &sB[q][row * 64 + (((h * 4 + fk) ^ sx) << 3)]);
        }
    };
    // 16-MFMA cluster: rows mbase..mbase+3 (of 8), cols nbase..nbase+1 (of 4)
    auto mmq = [&](bf16x8 (&a)[4][2], bf16x8 (&b)[2][2], int mbase, int nbase) {
        __builtin_amdgcn_s_setprio(1);
#pragma unroll
        for (int mt = 0; mt < 4; ++mt)
#pragma unroll
            for (int nt = 0; nt < 2; ++nt)
#pragma unroll
                for (int h = 0; h < 2; ++h)
                    acc[mbase + mt][nbase + nt] = __builtin_amdgcn_mfma_f32_16x16x32_bf16(
                        a[mt][h], b[nt][h], acc[mbase + mt][nbase + nt], 0, 0, 0);
        __builtin_amdgcn_s_setprio(0);
    };

    // ------------- prologue: B0,A0 full; B1 full; tile0 regs ---------------
    stage(Bb, &sB[0][0], 0, 0); stage(Bb, &sB[0][0], 0, 1);
    stage(Ab, &sA[0][0], 0, 0); stage(Ab, &sA[0][0], 0, 1);
    stage(Bb, &sB[1][0], 1, 0); stage(Bb, &sB[1][0], 1, 1);
    VMC(4);                       // B0,A0 landed; B1 (4 loads) in flight
    BAR;
    rdB(b01[0], 0, 0);            // tile0 b01  (plays prev-ph7)
    rdA(af_lo, 0, 0);             // tile0 af_lo (plays prev-ph8)

    const int NITER = K >> 7;     // K=1024 -> 8 iterations of 2 K-tiles
    for (int it = 0; it < NITER; ++it) {
        const int u = it * 2;     // even: tile u parity 0, tile u+1 parity 1
        // ---------------- K-tile u (LDS q=0, b01[0]) ----------------
        // ph1: read RB23(u); stage A(u+1)h0
        rdB(b23, 0, 2);
        stage(Ab, &sA[1][0], u + 1, 0);
        BAR; LGK(4);
        mmq(af_lo, b01[0], 0, 0);                    // q00
        BAR;
        // ph2: read RA_hi(u); stage A(u+1)h1
        rdA(af_hi, 0, 4);
        stage(Ab, &sA[1][0], u + 1, 1);
        BAR; LGK(8);
        mmq(af_lo, b23, 0, 2);                       // q01
        BAR;
        // ph3: vmcnt -> B(u+1) landed; read RB01(u+1); stage B(u+2)h0
        VMC(4);
        rdB(b01[1], 1, 0);
        stage(Bb, &sB[0][0], u + 2, 0);
        BAR; LGK(4);
        mmq(af_hi, b23, 4, 2);                       // q11
        BAR;
        // ph4: vmcnt -> A(u+1) landed; read RA_lo(u+1); stage B(u+2)h1
        VMC(2);
        rdA(af_lo, 1, 0);
        stage(Bb, &sB[0][0], u + 2, 1);
        BAR; LGK(8);
        mmq(af_hi, b01[0], 4, 0);                    // q10
        BAR;
        // ---------------- K-tile u+1 (LDS q=1, b01[1]) ----------------
        // ph5: read RB23(u+1); stage A(u+2)h0
        rdB(b23, 1, 2);
        stage(Ab, &sA[0][0], u + 2, 0);
        BAR; LGK(4);
        mmq(af_lo, b01[1], 0, 0);                    // q00
        BAR;
        // ph6: read RA_hi(u+1); stage A(u+2)h1
        rdA(af_hi, 1, 4);
        stage(Ab, &sA[0][0], u + 2, 1);
        BAR; LGK(8);
        mmq(af_lo, b23, 0, 2);                       // q01
        BAR;
        // ph7: vmcnt -> B(u+2) landed; read RB01(u+2); stage B(u+3)h0
        VMC(4);
        rdB(b01[0], 0, 0);
        stage(Bb, &sB[1][0], u + 3, 0);
        BAR; LGK(4);
        mmq(af_hi, b23, 4, 2);                       // q11
        BAR;
        // ph8: vmcnt -> A(u+2) landed; read RA_lo(u+2); stage B(u+3)h1
        VMC(2);
        rdA(af_lo, 0, 0);
        stage(Bb, &sB[1][0], u + 3, 1);
        BAR; LGK(8);
        mmq(af_hi, b01[1], 4, 0);                    // q10
        BAR;
        // (final iteration stages/reads tiles NT..NT+1: addresses stay inside
        //  the workspace (adjacent regions); garbage values never consumed)
    }

    // C/D layout 16x16x32 (verified m89/m91): col=lane&15, row=(lane>>4)*4+r
    const long mb = bm * 256 + wm * 128 + (fk << 2);
    const long nb = bn * 256 + wn * 64 + fr;
#pragma unroll
    for (int mt = 0; mt < 8; ++mt)
#pragma unroll
        for (int nt = 0; nt < 4; ++nt)
#pragma unroll
            for (int r = 0; r < 4; ++r)
                store_c(C, (mb + mt * 16 + r) * (long)N + nb + nt * 16, acc[mt][nt][r]);
}

// --------------------------- bf16 NT GEMM (GEMM2) --------------------------
template <int BM, int BN, typename CT>
__global__ __launch_bounds__(256) void gemm_bt(const unsigned short* __restrict__ A,
                                               const unsigned short* __restrict__ B,
                                               CT* __restrict__ C,
                                               int M, int N, int K) {
    constexpr int MI = BM / 64;
    constexpr int NJ = BN / 64;
    __shared__ __align__(16) unsigned short As[BM * 64];
    __shared__ __align__(16) unsigned short Bs[BN * 64];

    const int tid  = threadIdx.x;
    const int lane = tid & 63;
    const int wave = tid >> 6;
    const long bm  = blockIdx.y;
    const long bn  = blockIdx.x;
    const int wm   = (wave >> 1) * (BM / 2);
    const int wn   = (wave & 1) * (BN / 2);

    f32x16 acc[MI][NJ] = {};

    const unsigned short* Ab = A + bm * BM * (long)K;
    const unsigned short* Bb = B + bn * BN * (long)K;

    const int srow  = tid >> 3;
    const int sgcol = ((tid & 7) ^ (srow & 7)) << 3;

    for (int k0 = 0; k0 < K; k0 += 64) {
#pragma unroll
        for (int r = 0; r < BM / 32; ++r)
            __builtin_amdgcn_global_load_lds(
                (gbl_void*)(Ab + (long)(r * 32 + srow) * K + k0 + sgcol),
                (lds_void*)(As + (r * 256 + wave * 64) * 8), 16, 0, 0);
#pragma unroll
        for (int r = 0; r < BN / 32; ++r)
            __builtin_amdgcn_global_load_lds(
                (gbl_void*)(Bb + (long)(r * 32 + srow) * K + k0 + sgcol),
                (lds_void*)(Bs + (r * 256 + wave * 64) * 8), 16, 0, 0);
        __syncthreads();

        const int arow = lane & 31;
        const int kh   = lane >> 5;
#pragma unroll
        for (int kk = 0; kk < 4; ++kk) {
            const int c  = kk * 2 + kh;
            const int sw = (c ^ (lane & 7)) << 3;
            bf16x8 af[MI], bfr[NJ];
#pragma unroll
            for (int i = 0; i < MI; ++i)
                af[i] = *reinterpret_cast<const bf16x8*>(As + (wm + i * 32 + arow) * 64 + sw);
#pragma unroll
            for (int j = 0; j < NJ; ++j)
                bfr[j] = *reinterpret_cast<const bf16x8*>(Bs + (wn + j * 32 + arow) * 64 + sw);
#pragma unroll
            for (int i = 0; i < MI; ++i)
#pragma unroll
                for (int j = 0; j < NJ; ++j)
                    acc[i][j] = __builtin_amdgcn_mfma_f32_32x32x16_bf16(af[i], bfr[j], acc[i][j], 0, 0, 0);
        }
        __syncthreads();
    }

    const long mbase = bm * BM + wm + ((lane >> 5) << 2);
    const long nbase = bn * BN + wn + (lane & 31);
#pragma unroll
    for (int i = 0; i < MI; ++i)
#pragma unroll
        for (int j = 0; j < NJ; ++j)
#pragma unroll
            for (int r = 0; r < 16; ++r) {
                const long row = mbase + i * 32 + (r & 3) + 8 * (r >> 2);
                store_c(C, row * (long)N + nbase + j * 32, acc[i][j][r]);
            }
}

// ------------------- per-row head attention + scatter ----------------------
__global__ __launch_bounds__(256) void attn_rowlocal(const unsigned short* __restrict__ qkv,
                                                     unsigned short* __restrict__ out3) {
    __shared__ __align__(16) unsigned short rows[4 * 3072];  // 24 KB, swizzled
    __shared__ float attnS[4][16][17];                       // padded

    const int tid  = threadIdx.x;
    const int lane = tid & 63;
    const int wave = tid >> 6;
    const int m0   = blockIdx.x * 4;

    {   // cooperative load: LDS slot S gets global chunk (S&~7)|((S&7)^((S>>3)&7))
        const uint4* src = reinterpret_cast<const uint4*>(qkv + (long)m0 * 3072);
        uint4* dst = reinterpret_cast<uint4*>(rows);
#pragma unroll
        for (int c = 0; c < 6; ++c) {
            const int S  = c * 256 + tid;
            const int gs = (S & ~7) | ((S & 7) ^ ((S >> 3) & 7));
            dst[S] = src[gs];
        }
    }
    __syncthreads();

    const int m = m0 + wave;
    const int b = m >> 11;
    const int t = m & 2047;
    const unsigned short* rw = rows + wave * 3072;

    const int i  = lane & 15;
    const int j0 = (lane >> 4) << 2;
    float sc[4] = {0.f, 0.f, 0.f, 0.f};
#pragma unroll
    for (int c8 = 0; c8 < 8; ++c8) {
        uint4 qu = *reinterpret_cast<const uint4*>(rw + i * 64 + ((c8 ^ (i & 7)) << 3));
        float qf[8];
        unpack8(qu, qf);
#pragma unroll
        for (int jj = 0; jj < 4; ++jj) {
            const int vi = 16 + j0 + jj;
            uint4 ku = *reinterpret_cast<const uint4*>(rw + vi * 64 + ((c8 ^ (vi & 7)) << 3));
            float kf[8];
            unpack8(ku, kf);
#pragma unroll
            for (int d = 0; d < 8; ++d) sc[jj] += qf[d] * kf[d];
        }
    }
#pragma unroll
    for (int jj = 0; jj < 4; ++jj) sc[jj] *= 0.125f;

    float mx = fmaxf(fmaxf(sc[0], sc[1]), fmaxf(sc[2], sc[3]));
    mx = fmaxf(mx, __shfl_xor(mx, 16));
    mx = fmaxf(mx, __shfl_xor(mx, 32));
    float sum = 0.f;
#pragma unroll
    for (int jj = 0; jj < 4; ++jj) { sc[jj] = __expf(sc[jj] - mx); sum += sc[jj]; }
    sum += __shfl_xor(sum, 16);
    sum += __shfl_xor(sum, 32);
    const float inv = 1.0f / sum;
#pragma unroll
    for (int jj = 0; jj < 4; ++jj) attnS[wave][i][j0 + jj] = sc[jj] * inv;
    __syncthreads();

    const int oi = lane >> 2;
    const int s0 = (lane & 3) << 4;
    const int c0 = (lane & 3) << 1;
    float o[16];
#pragma unroll
    for (int ss = 0; ss < 16; ++ss) o[ss] = 0.f;
#pragma unroll
    for (int j = 0; j < 16; ++j) {
        const float a  = attnS[wave][oi][j];
        const int   vi = 32 + j;
        uint4 v0 = *reinterpret_cast<const uint4*>(rw + vi * 64 + (((c0)     ^ (vi & 7)) << 3));
        uint4 v1 = *reinterpret_cast<const uint4*>(rw + vi * 64 + (((c0 + 1) ^ (vi & 7)) << 3));
        float vf[16];
        unpack8(v0, vf);
        unpack8(v1, vf + 8);
#pragma unroll
        for (int ss = 0; ss < 16; ++ss) o[ss] += a * vf[ss];
    }

    uint4 r0, r1;
    r0.x = pack2(o[0],  o[1]);  r0.y = pack2(o[2],  o[3]);
    r0.z = pack2(o[4],  o[5]);  r0.w = pack2(o[6],  o[7]);
    r1.x = pack2(o[8],  o[9]);  r1.y = pack2(o[10], o[11]);
    r1.z = pack2(o[12], o[13]); r1.w = pack2(o[14], o[15]);

    const long base = (long)b * (2048 * 1024)
                    + (long)(oi * 128 + (t >> 4)) * 1024
                    + 64 * (t & 15) + s0;
    *reinterpret_cast<uint4*>(out3 + base)     = r0;
    *reinterpret_cast<uint4*>(out3 + base + 8) = r1;
}

// ------------------------------- launcher ----------------------------------
extern "C" void kernel_launch(void* const* d_in, const int* in_sizes, int n_in,
                              void* d_out, int out_size, void* d_ws, size_t ws_size,
                              hipStream_t stream) {
    const float* x     = (const float*)d_in[0];   // (4,2048,1024)
    const float* Wqkv  = (const float*)d_in[1];   // (3072,1024)
    const float* Wproj = (const float*)d_in[2];   // (1024,1024)
    float* out = (float*)d_out;                   // (4,2048,1024) fp32

    char* ws = (char*)d_ws;
    unsigned short* xb     = (unsigned short*)(ws);               // 16.0 MiB
    unsigned short* wqkvb  = (unsigned short*)(ws + 16777216);    //  6.0 MiB
    unsigned short* wprojb = (unsigned short*)(ws + 23068672);    //  2.0 MiB
    unsigned short* qkvb   = (unsigned short*)(ws + 25165824);    // 48.0 MiB
    unsigned short* out3b  = (unsigned short*)(ws + 75497472);    // 16.0 MiB

    // all three fp32->bf16 casts in one dispatch (3,145,728 float4s)
    cvt_all<<<dim3(12288), dim3(256), 0, stream>>>(x, Wqkv, Wproj, xb, wqkvb, wprojb);

    // qkv = x @ Wqkv^T : M=8192, N=3072, K=1024  (256x256 8-phase pipelined)
    gemm256pp<unsigned short><<<dim3(384), dim3(512), 0, stream>>>(
        xb, wqkvb, qkvb, 8192, 3072, 1024, 12);

    attn_rowlocal<<<dim3(2048), dim3(256), 0, stream>>>(qkvb, out3b);

    // out = out3 @ Wproj^T : M=8192, N=1024, K=1024  (64x128 tiles, 4 blk/CU)
    gemm_bt<64, 128, float><<<dim3(8, 128), dim3(256), 0, stream>>>(
        out3b, wprojb, out, 8192, 1024, 1024);
}

// Round 5
// 230.997 us; speedup vs baseline: 1.1736x; 1.1736x over previous
//
#include <hip/hip_runtime.h>

// ---------------------------------------------------------------------------
// MultiheadSelfAttention (row-local head-mixing variant), MI355X / gfx950.
// Round 13: phase-ahead pipelined GEMM (attempt #4, register-budget-proven).
// R12's schedule was right but spilled (WRITE_SIZE 173MB = scratch).  Now:
// tile 256x128, 8 waves (4Mx2N), wave tile 64x64 -> acc[4][4]=64 (AGPR),
// live frags af+af'+b01+b23 ~96 VGPR < 128 cap.  2 phases/K-tile; each
// phase's MFMA consumes ONLY previous-phase ds_reads (no lgkm wait before
// MFMA); lgkm(0) at phase end.  Stages: A(u+2) in ph_a, B(u+2) in ph_b,
// vmcnt(4) once per K-tile (never 0); clamped tail keeps counts uniform.
// LDS 96 KiB, 1 blk/CU; exact-round grids (768 / 256 blocks).
// Both GEMMs use this kernel.  attn / cvt unchanged.
// ---------------------------------------------------------------------------

typedef __bf16 bf16x8 __attribute__((ext_vector_type(8)));
typedef float  f32x4  __attribute__((ext_vector_type(4)));

typedef __attribute__((address_space(3))) void       lds_void;
typedef const __attribute__((address_space(1))) void gbl_void;

__device__ __forceinline__ unsigned short f2b(float f) {
    unsigned int u = __builtin_bit_cast(unsigned int, f);
    return (unsigned short)((u + 0x7FFFu + ((u >> 16) & 1u)) >> 16);  // RNE
}
__device__ __forceinline__ unsigned int pack2(float a, float b) {
    return (unsigned int)f2b(a) | ((unsigned int)f2b(b) << 16);
}
__device__ __forceinline__ void unpack8(uint4 u, float* f) {
    unsigned int w[4] = {u.x, u.y, u.z, u.w};
#pragma unroll
    for (int a = 0; a < 4; ++a) {
        union { unsigned int i; float f; } lo, hi;
        lo.i = w[a] << 16;
        hi.i = w[a] & 0xFFFF0000u;
        f[a * 2]     = lo.f;
        f[a * 2 + 1] = hi.f;
    }
}

// ------------------------- fused fp32 -> bf16 cast -------------------------
__global__ __launch_bounds__(256) void cvt_all(const float* __restrict__ x,
                                               const float* __restrict__ wqkv,
                                               const float* __restrict__ wproj,
                                               unsigned short* __restrict__ xb,
                                               unsigned short* __restrict__ wqkvb,
                                               unsigned short* __restrict__ wprojb) {
    int i = blockIdx.x * 256 + threadIdx.x;
    const float* src;
    unsigned short* dst;
    if (i < 2097152)      { src = x;     dst = xb;                   }
    else if (i < 2883584) { src = wqkv;  dst = wqkvb;  i -= 2097152; }
    else                  { src = wproj; dst = wprojb; i -= 2883584; }
    float4 f = reinterpret_cast<const float4*>(src)[i];
    ushort4 u;
    u.x = f2b(f.x); u.y = f2b(f.y); u.z = f2b(f.z); u.w = f2b(f.w);
    reinterpret_cast<ushort4*>(dst)[i] = u;
}

__device__ __forceinline__ void store_c(float* C, long idx, float v)          { C[idx] = v; }
__device__ __forceinline__ void store_c(unsigned short* C, long idx, float v) { C[idx] = f2b(v); }

// -------------- 256x128 phase-ahead pipelined bf16 NT GEMM -----------------
// C[m,n] = sum_k A[m,k]*B[n,k].  A: MxK rm, B: NxK rm (bf16 bits as ushort).
// 512 thr = 8 waves (4M x 2N); wave tile 64x64 = acc[4][4] of 16x16x32.
// LDS: 2 x (A 256x64 32KB + B 128x64 16KB) = 96 KiB.  Row = 8 chunks of 16B,
// chunk c of row r at slot c^(r&7); linear gload_lds dest, inverse-swizzled
// global source, swizzled ds_read (R11-verified: conflicts = 0).
// Per K-tile u (p = u&1):
//  ph_a: stage A(u+2)->sA[p]; read b23(u) [4]; MFMA-left (af,b01) x16;
//        lgkm(0); vmcnt(4)  [B(u+1) landed, A(u+2) in flight]; barrier.
//  ph_b: stage B(u+2)->sB[p]; read af(u+1) [8] + b01(u+1) [4] from [p^1];
//        MFMA-right (af,b23) x16; lgkm(0); barrier.
// MFMA operands are ALWAYS prior-phase reads -> no wait before MFMA.
#define BAR    __builtin_amdgcn_s_barrier()
#define LGK0   asm volatile("s_waitcnt lgkmcnt(0)" ::: "memory")
#define VMC(n) asm volatile("s_waitcnt vmcnt(" #n ")" ::: "memory")

template <typename CT>
__global__ __launch_bounds__(512, 2) void gemm_pl(const unsigned short* __restrict__ A,
                                                  const unsigned short* __restrict__ B,
                                                  CT* __restrict__ C,
                                                  int M, int N, int K, int NBX) {
    __shared__ __align__(16) unsigned short sA[2][16384];  // 2 x 32 KiB (256x64)
    __shared__ __align__(16) unsigned short sB[2][8192];   // 2 x 16 KiB (128x64)

    const int tid  = threadIdx.x;
    const int lane = tid & 63;
    const int wave = tid >> 6;
    const int wm   = (wave >> 1) * 64;     // 0,64,128,192  (M quarter)
    const int wn   = (wave & 1) * 64;      // 0,64          (N half)

    // bijective XCD swizzle (gridDim.x % 8 == 0)
    const int nwg = gridDim.x;
    const int cpx = nwg >> 3;
    const int swz = ((int)blockIdx.x & 7) * cpx + ((int)blockIdx.x >> 3);
    const long bm = swz / NBX;
    const long bn = swz % NBX;

    const unsigned short* Ab = A + bm * 256 * (long)K;
    const unsigned short* Bb = B + bn * 128 * (long)K;

    const int NT = K >> 6;                 // 16 K-tiles

    f32x4 acc[4][4] = {};

    const int sr = tid >> 3;                           // staging row 0..63
    const int sc = ((tid & 7) ^ (sr & 7)) << 3;        // inverse-swizzled chunk

    auto stageA = [&](int p, int t) {                  // 4 loads: rows j*64+sr
        const unsigned short* g = Ab + (long)sr * K + (long)t * 64 + sc;
        unsigned short* l = &sA[p][0] + wave * 512;
#pragma unroll
        for (int j = 0; j < 4; ++j)
            __builtin_amdgcn_global_load_lds((gbl_void*)(g + (long)j * 64 * K),
                                             (lds_void*)(l + j * 4096), 16, 0, 0);
    };
    auto stageB = [&](int p, int t) {                  // 2 loads: rows j*64+sr
        const unsigned short* g = Bb + (long)sr * K + (long)t * 64 + sc;
        unsigned short* l = &sB[p][0] + wave * 512;
#pragma unroll
        for (int j = 0; j < 2; ++j)
            __builtin_amdgcn_global_load_lds((gbl_void*)(g + (long)j * 64 * K),
                                             (lds_void*)(l + j * 4096), 16, 0, 0);
    };

    const int fr = lane & 15;              // fragment row (A) / col (B)
    const int fk = lane >> 4;              // k-chunk 0..3

    bf16x8 af[4][2], afn[4][2], b01[2][2], b23[2][2];

    auto rdA = [&](bf16x8 (&dst)[4][2], int p) {
#pragma unroll
        for (int mt = 0; mt < 4; ++mt) {
            const int row = wm + mt * 16 + fr;
#pragma unroll
            for (int h = 0; h < 2; ++h)
                dst[mt][h] = *reinterpret_cast<const bf16x8*>(
                    &sA[p][row * 64 + (((h * 4 + fk) ^ (row & 7)) << 3)]);
        }
    };
    auto rdB = [&](bf16x8 (&dst)[2][2], int p, int nbase) {
#pragma unroll
        for (int nt = 0; nt < 2; ++nt) {
            const int row = wn + (nbase + nt) * 16 + fr;
#pragma unroll
            for (int h = 0; h < 2; ++h)
                dst[nt][h] = *reinterpret_cast<const bf16x8*>(
                    &sB[p][row * 64 + (((h * 4 + fk) ^ (row & 7)) << 3)]);
        }
    };
    auto mm16 = [&](bf16x8 (&a)[4][2], bf16x8 (&b)[2][2], int nbase) {
        __builtin_amdgcn_s_setprio(1);
#pragma unroll
        for (int mt = 0; mt < 4; ++mt)
#pragma unroll
            for (int nt = 0; nt < 2; ++nt)
#pragma unroll
                for (int h = 0; h < 2; ++h)
                    acc[mt][nbase + nt] = __builtin_amdgcn_mfma_f32_16x16x32_bf16(
                        a[mt][h], b[nt][h], acc[mt][nbase + nt], 0, 0, 0);
        __builtin_amdgcn_s_setprio(0);
    };

    // ------------------------------ prologue -------------------------------
    stageA(0, 0); stageB(0, 0);            // 6 loads: tile 0
    stageA(1, 1); stageB(1, 1);            // 6 loads: tile 1
    VMC(6);                                // tile 0 landed; tile 1 in flight
    BAR;
    rdA(af, 0); rdB(b01, 0, 0);            // tile 0 operands (left half)
    LGK0;
    BAR;

    // ------------------------------ main loop ------------------------------
    for (int u = 0; u < NT; ++u) {
        const int p = u & 1;
        const int t2 = (u + 2 < NT) ? (u + 2) : (NT - 1);   // clamp (uniform counts)
        // ---- ph_a: MFMA-left(u) ----
        stageA(p, t2);
        rdB(b23, p, 2);
        mm16(af, b01, 0);
        LGK0;
        VMC(4);          // B(u+1) landed; A(u+2) (4 loads) stays in flight
        BAR;
        // ---- ph_b: MFMA-right(u) ----
        stageB(p, t2);
        if (u + 1 < NT) { rdA(afn, p ^ 1); rdB(b01, p ^ 1, 0); }
        mm16(af, b23, 2);
        LGK0;
        BAR;
#pragma unroll
        for (int mt = 0; mt < 4; ++mt)
#pragma unroll
            for (int h = 0; h < 2; ++h)
                af[mt][h] = afn[mt][h];
    }

    // C/D layout 16x16x32 (verified m89/m91): col=lane&15, row=(lane>>4)*4+r
    const long mb = bm * 256 + wm + (fk << 2);
    const long nb = bn * 128 + wn + fr;
#pragma unroll
    for (int mt = 0; mt < 4; ++mt)
#pragma unroll
        for (int nt = 0; nt < 4; ++nt)
#pragma unroll
            for (int r = 0; r < 4; ++r)
                store_c(C, (mb + mt * 16 + r) * (long)N + nb + nt * 16, acc[mt][nt][r]);
}

// ------------------- per-row head attention + scatter ----------------------
// qkv row m=(b,t): q=e[0,1024), k=e[1024,2048), v=e[2048,3072); h=e/64%16.
// scores[i][j]=0.125*dot64(q_i,k_j); softmax over j; out[i][s]=sum_j a*v.
// Scatter: out[b,t,h,s] -> out3[b, h*128 + t/16, 64*(t%16)+s].
// rows[] is XOR chunk-swizzled: chunk c of 64-elem vector vi at c^(vi&7).
__global__ __launch_bounds__(256) void attn_rowlocal(const unsigned short* __restrict__ qkv,
                                                     unsigned short* __restrict__ out3) {
    __shared__ __align__(16) unsigned short rows[4 * 3072];  // 24 KB, swizzled
    __shared__ float attnS[4][16][17];                       // padded

    const int tid  = threadIdx.x;
    const int lane = tid & 63;
    const int wave = tid >> 6;
    const int m0   = blockIdx.x * 4;

    {   // cooperative load: LDS slot S gets global chunk (S&~7)|((S&7)^((S>>3)&7))
        const uint4* src = reinterpret_cast<const uint4*>(qkv + (long)m0 * 3072);
        uint4* dst = reinterpret_cast<uint4*>(rows);
#pragma unroll
        for (int c = 0; c < 6; ++c) {
            const int S  = c * 256 + tid;
            const int gs = (S & ~7) | ((S & 7) ^ ((S >> 3) & 7));
            dst[S] = src[gs];
        }
    }
    __syncthreads();

    const int m = m0 + wave;
    const int b = m >> 11;
    const int t = m & 2047;
    const unsigned short* rw = rows + wave * 3072;

    const int i  = lane & 15;
    const int j0 = (lane >> 4) << 2;
    float sc[4] = {0.f, 0.f, 0.f, 0.f};
#pragma unroll
    for (int c8 = 0; c8 < 8; ++c8) {
        uint4 qu = *reinterpret_cast<const uint4*>(rw + i * 64 + ((c8 ^ (i & 7)) << 3));
        float qf[8];
        unpack8(qu, qf);
#pragma unroll
        for (int jj = 0; jj < 4; ++jj) {
            const int vi = 16 + j0 + jj;
            uint4 ku = *reinterpret_cast<const uint4*>(rw + vi * 64 + ((c8 ^ (vi & 7)) << 3));
            float kf[8];
            unpack8(ku, kf);
#pragma unroll
            for (int d = 0; d < 8; ++d) sc[jj] += qf[d] * kf[d];
        }
    }
#pragma unroll
    for (int jj = 0; jj < 4; ++jj) sc[jj] *= 0.125f;

    float mx = fmaxf(fmaxf(sc[0], sc[1]), fmaxf(sc[2], sc[3]));
    mx = fmaxf(mx, __shfl_xor(mx, 16));
    mx = fmaxf(mx, __shfl_xor(mx, 32));
    float sum = 0.f;
#pragma unroll
    for (int jj = 0; jj < 4; ++jj) { sc[jj] = __expf(sc[jj] - mx); sum += sc[jj]; }
    sum += __shfl_xor(sum, 16);
    sum += __shfl_xor(sum, 32);
    const float inv = 1.0f / sum;
#pragma unroll
    for (int jj = 0; jj < 4; ++jj) attnS[wave][i][j0 + jj] = sc[jj] * inv;
    __syncthreads();

    const int oi = lane >> 2;
    const int s0 = (lane & 3) << 4;
    const int c0 = (lane & 3) << 1;
    float o[16];
#pragma unroll
    for (int ss = 0; ss < 16; ++ss) o[ss] = 0.f;
#pragma unroll
    for (int j = 0; j < 16; ++j) {
        const float a  = attnS[wave][oi][j];
        const int   vi = 32 + j;
        uint4 v0 = *reinterpret_cast<const uint4*>(rw + vi * 64 + (((c0)     ^ (vi & 7)) << 3));
        uint4 v1 = *reinterpret_cast<const uint4*>(rw + vi * 64 + (((c0 + 1) ^ (vi & 7)) << 3));
        float vf[16];
        unpack8(v0, vf);
        unpack8(v1, vf + 8);
#pragma unroll
        for (int ss = 0; ss < 16; ++ss) o[ss] += a * vf[ss];
    }

    uint4 r0, r1;
    r0.x = pack2(o[0],  o[1]);  r0.y = pack2(o[2],  o[3]);
    r0.z = pack2(o[4],  o[5]);  r0.w = pack2(o[6],  o[7]);
    r1.x = pack2(o[8],  o[9]);  r1.y = pack2(o[10], o[11]);
    r1.z = pack2(o[12], o[13]); r1.w = pack2(o[14], o[15]);

    const long base = (long)b * (2048 * 1024)
                    + (long)(oi * 128 + (t >> 4)) * 1024
                    + 64 * (t & 15) + s0;
    *reinterpret_cast<uint4*>(out3 + base)     = r0;
    *reinterpret_cast<uint4*>(out3 + base + 8) = r1;
}

// ------------------------------- launcher ----------------------------------
extern "C" void kernel_launch(void* const* d_in, const int* in_sizes, int n_in,
                              void* d_out, int out_size, void* d_ws, size_t ws_size,
                              hipStream_t stream) {
    const float* x     = (const float*)d_in[0];   // (4,2048,1024)
    const float* Wqkv  = (const float*)d_in[1];   // (3072,1024)
    const float* Wproj = (const float*)d_in[2];   // (1024,1024)
    float* out = (float*)d_out;                   // (4,2048,1024) fp32

    char* ws = (char*)d_ws;
    unsigned short* xb     = (unsigned short*)(ws);               // 16.0 MiB
    unsigned short* wqkvb  = (unsigned short*)(ws + 16777216);    //  6.0 MiB
    unsigned short* wprojb = (unsigned short*)(ws + 23068672);    //  2.0 MiB
    unsigned short* qkvb   = (unsigned short*)(ws + 25165824);    // 48.0 MiB
    unsigned short* out3b  = (unsigned short*)(ws + 75497472);    // 16.0 MiB

    // all three fp32->bf16 casts in one dispatch (3,145,728 float4s)
    cvt_all<<<dim3(12288), dim3(256), 0, stream>>>(x, Wqkv, Wproj, xb, wqkvb, wprojb);

    // qkv = x @ Wqkv^T : M=8192, N=3072, K=1024  (256x128 tiles, 768 = 3 rounds)
    gemm_pl<unsigned short><<<dim3(768), dim3(512), 0, stream>>>(
        xb, wqkvb, qkvb, 8192, 3072, 1024, 24);

    attn_rowlocal<<<dim3(2048), dim3(256), 0, stream>>>(qkvb, out3b);

    // out = out3 @ Wproj^T : M=8192, N=1024, K=1024  (256x128 tiles, 256 = 1 round)
    gemm_pl<float><<<dim3(256), dim3(512), 0, stream>>>(
        out3b, wprojb, out, 8192, 1024, 1024, 8);
}

// Round 6
// 192.902 us; speedup vs baseline: 1.4054x; 1.1975x over previous
//
#include <hip/hip_runtime.h>

// ---------------------------------------------------------------------------
// MultiheadSelfAttention (row-local head-mixing variant), MI355X / gfx950.
// Round 14: consolidation.  Pipeline arc (R9-R13) abandoned: 4 attempts all
// <= the 2-barrier 3blk/CU structure (implicit cross-block overlap, m114).
// GEMM1 = R10's proven 128x256 (60us, 858 TF ~ structure ceiling).
// GEMM2 64x128 -> 128x128: frag-reads/MFMA 1.5 -> 1.0, 16 MFMA/K-step,
// grid 8x64=512 = 2 exact rounds at 3blk/CU occupancy.
// ---------------------------------------------------------------------------

typedef __bf16 bf16x8 __attribute__((ext_vector_type(8)));
typedef float  f32x16 __attribute__((ext_vector_type(16)));

typedef __attribute__((address_space(3))) void       lds_void;
typedef const __attribute__((address_space(1))) void gbl_void;

__device__ __forceinline__ unsigned short f2b(float f) {
    unsigned int u = __builtin_bit_cast(unsigned int, f);
    return (unsigned short)((u + 0x7FFFu + ((u >> 16) & 1u)) >> 16);  // RNE
}
__device__ __forceinline__ unsigned int pack2(float a, float b) {
    return (unsigned int)f2b(a) | ((unsigned int)f2b(b) << 16);
}
__device__ __forceinline__ void unpack8(uint4 u, float* f) {
    unsigned int w[4] = {u.x, u.y, u.z, u.w};
#pragma unroll
    for (int a = 0; a < 4; ++a) {
        union { unsigned int i; float f; } lo, hi;
        lo.i = w[a] << 16;
        hi.i = w[a] & 0xFFFF0000u;
        f[a * 2]     = lo.f;
        f[a * 2 + 1] = hi.f;
    }
}

// ------------------------- fused fp32 -> bf16 cast -------------------------
__global__ __launch_bounds__(256) void cvt_all(const float* __restrict__ x,
                                               const float* __restrict__ wqkv,
                                               const float* __restrict__ wproj,
                                               unsigned short* __restrict__ xb,
                                               unsigned short* __restrict__ wqkvb,
                                               unsigned short* __restrict__ wprojb) {
    int i = blockIdx.x * 256 + threadIdx.x;
    const float* src;
    unsigned short* dst;
    if (i < 2097152)      { src = x;     dst = xb;                   }
    else if (i < 2883584) { src = wqkv;  dst = wqkvb;  i -= 2097152; }
    else                  { src = wproj; dst = wprojb; i -= 2883584; }
    float4 f = reinterpret_cast<const float4*>(src)[i];
    ushort4 u;
    u.x = f2b(f.x); u.y = f2b(f.y); u.z = f2b(f.z); u.w = f2b(f.w);
    reinterpret_cast<ushort4*>(dst)[i] = u;
}

// --------------------------- bf16 NT GEMM ----------------------------------
// C[m,n] = sum_k A[m,k]*B[n,k].  A: MxK rm, B: NxK rm (bf16 bits as ushort).
// Block tile BMxBN, BK=64.  4 waves 2x2; wave tile (BM/2)x(BN/2) as MIxNJ
// tiles of 32x32x16 MFMA (MI=BM/64, NJ=BN/64).  LDS rows = 8 chunks of 16B;
// chunk c of row r at slot c^(r&7) -> conflict-free staging, swizzled reads.
__device__ __forceinline__ void store_c(float* C, long idx, float v)          { C[idx] = v; }
__device__ __forceinline__ void store_c(unsigned short* C, long idx, float v) { C[idx] = f2b(v); }

template <int BM, int BN, typename CT>
__global__ __launch_bounds__(256, 3) void gemm_bt(const unsigned short* __restrict__ A,
                                                  const unsigned short* __restrict__ B,
                                                  CT* __restrict__ C,
                                                  int M, int N, int K) {
    constexpr int MI = BM / 64;                    // 32-row MFMA tiles per wave (M)
    constexpr int NJ = BN / 64;                    // 32-col MFMA tiles per wave (N)
    __shared__ __align__(16) unsigned short As[BM * 64];
    __shared__ __align__(16) unsigned short Bs[BN * 64];

    const int tid  = threadIdx.x;
    const int lane = tid & 63;
    const int wave = tid >> 6;
    const long bm  = blockIdx.y;
    const long bn  = blockIdx.x;
    const int wm   = (wave >> 1) * (BM / 2);
    const int wn   = (wave & 1) * (BN / 2);

    f32x16 acc[MI][NJ] = {};

    const unsigned short* Ab = A + bm * BM * (long)K;
    const unsigned short* Bb = B + bn * BN * (long)K;

    const int srow  = tid >> 3;                        // row within 32-row group
    const int sgcol = ((tid & 7) ^ (srow & 7)) << 3;   // swizzled SOURCE chunk

    for (int k0 = 0; k0 < K; k0 += 64) {
#pragma unroll
        for (int r = 0; r < BM / 32; ++r)
            __builtin_amdgcn_global_load_lds(
                (gbl_void*)(Ab + (long)(r * 32 + srow) * K + k0 + sgcol),
                (lds_void*)(As + (r * 256 + wave * 64) * 8), 16, 0, 0);
#pragma unroll
        for (int r = 0; r < BN / 32; ++r)
            __builtin_amdgcn_global_load_lds(
                (gbl_void*)(Bb + (long)(r * 32 + srow) * K + k0 + sgcol),
                (lds_void*)(Bs + (r * 256 + wave * 64) * 8), 16, 0, 0);
        __syncthreads();

        const int arow = lane & 31;
        const int kh   = lane >> 5;                    // k-half: k = kh*8 + j
#pragma unroll
        for (int kk = 0; kk < 4; ++kk) {               // 4 x K=16
            const int c  = kk * 2 + kh;                // logical chunk 0..7
            const int sw = (c ^ (lane & 7)) << 3;      // swizzled read offset
            bf16x8 af[MI], bfr[NJ];
#pragma unroll
            for (int i = 0; i < MI; ++i)
                af[i] = *reinterpret_cast<const bf16x8*>(As + (wm + i * 32 + arow) * 64 + sw);
#pragma unroll
            for (int j = 0; j < NJ; ++j)
                bfr[j] = *reinterpret_cast<const bf16x8*>(Bs + (wn + j * 32 + arow) * 64 + sw);
#pragma unroll
            for (int i = 0; i < MI; ++i)
#pragma unroll
                for (int j = 0; j < NJ; ++j)
                    acc[i][j] = __builtin_amdgcn_mfma_f32_32x32x16_bf16(af[i], bfr[j], acc[i][j], 0, 0, 0);
        }
        __syncthreads();
    }

    // C/D layout (verified m74/m101): col=lane&31, row=(r&3)+8*(r>>2)+4*(lane>>5)
    const long mbase = bm * BM + wm + ((lane >> 5) << 2);
    const long nbase = bn * BN + wn + (lane & 31);
#pragma unroll
    for (int i = 0; i < MI; ++i)
#pragma unroll
        for (int j = 0; j < NJ; ++j)
#pragma unroll
            for (int r = 0; r < 16; ++r) {
                const long row = mbase + i * 32 + (r & 3) + 8 * (r >> 2);
                store_c(C, row * (long)N + nbase + j * 32, acc[i][j][r]);
            }
}

// ------------------- per-row head attention + scatter ----------------------
// qkv row m=(b,t): q=e[0,1024), k=e[1024,2048), v=e[2048,3072); h=e/64%16.
// scores[i][j]=0.125*dot64(q_i,k_j); softmax over j; out[i][s]=sum_j a*v.
// Scatter: out[b,t,h,s] -> out3[b, h*128 + t/16, 64*(t%16)+s].
// rows[] is XOR chunk-swizzled: chunk c of 64-elem vector vi at c^(vi&7).
__global__ __launch_bounds__(256) void attn_rowlocal(const unsigned short* __restrict__ qkv,
                                                     unsigned short* __restrict__ out3) {
    __shared__ __align__(16) unsigned short rows[4 * 3072];  // 24 KB, swizzled
    __shared__ float attnS[4][16][17];                       // padded

    const int tid  = threadIdx.x;
    const int lane = tid & 63;
    const int wave = tid >> 6;
    const int m0   = blockIdx.x * 4;

    {   // cooperative load: LDS slot S gets global chunk (S&~7)|((S&7)^((S>>3)&7))
        const uint4* src = reinterpret_cast<const uint4*>(qkv + (long)m0 * 3072);
        uint4* dst = reinterpret_cast<uint4*>(rows);
#pragma unroll
        for (int c = 0; c < 6; ++c) {
            const int S  = c * 256 + tid;
            const int gs = (S & ~7) | ((S & 7) ^ ((S >> 3) & 7));
            dst[S] = src[gs];
        }
    }
    __syncthreads();

    const int m = m0 + wave;
    const int b = m >> 11;
    const int t = m & 2047;
    const unsigned short* rw = rows + wave * 3072;

    // scores: lane handles i = lane&15, j in [(lane>>4)*4, +4)
    const int i  = lane & 15;
    const int j0 = (lane >> 4) << 2;
    float sc[4] = {0.f, 0.f, 0.f, 0.f};
#pragma unroll
    for (int c8 = 0; c8 < 8; ++c8) {
        uint4 qu = *reinterpret_cast<const uint4*>(rw + i * 64 + ((c8 ^ (i & 7)) << 3));
        float qf[8];
        unpack8(qu, qf);
#pragma unroll
        for (int jj = 0; jj < 4; ++jj) {
            const int vi = 16 + j0 + jj;
            uint4 ku = *reinterpret_cast<const uint4*>(rw + vi * 64 + ((c8 ^ (vi & 7)) << 3));
            float kf[8];
            unpack8(ku, kf);
#pragma unroll
            for (int d = 0; d < 8; ++d) sc[jj] += qf[d] * kf[d];
        }
    }
#pragma unroll
    for (int jj = 0; jj < 4; ++jj) sc[jj] *= 0.125f;

    float mx = fmaxf(fmaxf(sc[0], sc[1]), fmaxf(sc[2], sc[3]));
    mx = fmaxf(mx, __shfl_xor(mx, 16));
    mx = fmaxf(mx, __shfl_xor(mx, 32));
    float sum = 0.f;
#pragma unroll
    for (int jj = 0; jj < 4; ++jj) { sc[jj] = __expf(sc[jj] - mx); sum += sc[jj]; }
    sum += __shfl_xor(sum, 16);
    sum += __shfl_xor(sum, 32);
    const float inv = 1.0f / sum;
#pragma unroll
    for (int jj = 0; jj < 4; ++jj) attnS[wave][i][j0 + jj] = sc[jj] * inv;
    __syncthreads();

    // out: lane handles head oi = lane>>2, s chunk s0 = (lane&3)*16
    const int oi = lane >> 2;
    const int s0 = (lane & 3) << 4;
    const int c0 = (lane & 3) << 1;
    float o[16];
#pragma unroll
    for (int ss = 0; ss < 16; ++ss) o[ss] = 0.f;
#pragma unroll
    for (int j = 0; j < 16; ++j) {
        const float a  = attnS[wave][oi][j];
        const int   vi = 32 + j;
        uint4 v0 = *reinterpret_cast<const uint4*>(rw + vi * 64 + (((c0)     ^ (vi & 7)) << 3));
        uint4 v1 = *reinterpret_cast<const uint4*>(rw + vi * 64 + (((c0 + 1) ^ (vi & 7)) << 3));
        float vf[16];
        unpack8(v0, vf);
        unpack8(v1, vf + 8);
#pragma unroll
        for (int ss = 0; ss < 16; ++ss) o[ss] += a * vf[ss];
    }

    uint4 r0, r1;
    r0.x = pack2(o[0],  o[1]);  r0.y = pack2(o[2],  o[3]);
    r0.z = pack2(o[4],  o[5]);  r0.w = pack2(o[6],  o[7]);
    r1.x = pack2(o[8],  o[9]);  r1.y = pack2(o[10], o[11]);
    r1.z = pack2(o[12], o[13]); r1.w = pack2(o[14], o[15]);

    const long base = (long)b * (2048 * 1024)
                    + (long)(oi * 128 + (t >> 4)) * 1024
                    + 64 * (t & 15) + s0;
    *reinterpret_cast<uint4*>(out3 + base)     = r0;
    *reinterpret_cast<uint4*>(out3 + base + 8) = r1;
}

// ------------------------------- launcher ----------------------------------
extern "C" void kernel_launch(void* const* d_in, const int* in_sizes, int n_in,
                              void* d_out, int out_size, void* d_ws, size_t ws_size,
                              hipStream_t stream) {
    const float* x     = (const float*)d_in[0];   // (4,2048,1024)
    const float* Wqkv  = (const float*)d_in[1];   // (3072,1024)
    const float* Wproj = (const float*)d_in[2];   // (1024,1024)
    float* out = (float*)d_out;                   // (4,2048,1024) fp32

    char* ws = (char*)d_ws;
    unsigned short* xb     = (unsigned short*)(ws);               // 16.0 MiB
    unsigned short* wqkvb  = (unsigned short*)(ws + 16777216);    //  6.0 MiB
    unsigned short* wprojb = (unsigned short*)(ws + 23068672);    //  2.0 MiB
    unsigned short* qkvb   = (unsigned short*)(ws + 25165824);    // 48.0 MiB
    unsigned short* out3b  = (unsigned short*)(ws + 75497472);    // 16.0 MiB

    // all three fp32->bf16 casts in one dispatch (3,145,728 float4s)
    cvt_all<<<dim3(12288), dim3(256), 0, stream>>>(x, Wqkv, Wproj, xb, wqkvb, wprojb);

    // qkv = x @ Wqkv^T : M=8192, N=3072, K=1024
    // 128x256 tiles -> 768 blocks = 3 blk/CU x 3 exact rounds, 0.75 frag/MFMA
    gemm_bt<128, 256, unsigned short><<<dim3(12, 64), dim3(256), 0, stream>>>(
        xb, wqkvb, qkvb, 8192, 3072, 1024);

    attn_rowlocal<<<dim3(2048), dim3(256), 0, stream>>>(qkvb, out3b);

    // out = out3 @ Wproj^T : M=8192, N=1024, K=1024
    // 128x128 tiles -> 512 blocks = 2 exact rounds, 1.0 frag/MFMA
    gemm_bt<128, 128, float><<<dim3(8, 64), dim3(256), 0, stream>>>(
        out3b, wprojb, out, 8192, 1024, 1024);
}

// Round 7
// 188.450 us; speedup vs baseline: 1.4386x; 1.0236x over previous
//
#include <hip/hip_runtime.h>

// ---------------------------------------------------------------------------
// MultiheadSelfAttention (row-local head-mixing variant), MI355X / gfx950.
// Round 15: XCD-chunked block swizzle (T1) on both GEMMs.  R14 arithmetic
// shows GEMM1 is partially staging-supply-bound (~590 MB through HBM+L3 at
// ~10 TB/s); same-bm blocks currently round-robin across XCDs so A panels
// are L3-served into every XCD's L2.  Remap: each XCD owns a contiguous bm
// range (8 A-panels = 2 MB, fits 4 MB L2) with bn-fastest order inside.
// GEMM kernels otherwise byte-identical to R14 (proven 2-barrier structure).
// ---------------------------------------------------------------------------

typedef __bf16 bf16x8 __attribute__((ext_vector_type(8)));
typedef float  f32x16 __attribute__((ext_vector_type(16)));

typedef __attribute__((address_space(3))) void       lds_void;
typedef const __attribute__((address_space(1))) void gbl_void;

__device__ __forceinline__ unsigned short f2b(float f) {
    unsigned int u = __builtin_bit_cast(unsigned int, f);
    return (unsigned short)((u + 0x7FFFu + ((u >> 16) & 1u)) >> 16);  // RNE
}
__device__ __forceinline__ unsigned int pack2(float a, float b) {
    return (unsigned int)f2b(a) | ((unsigned int)f2b(b) << 16);
}
__device__ __forceinline__ void unpack8(uint4 u, float* f) {
    unsigned int w[4] = {u.x, u.y, u.z, u.w};
#pragma unroll
    for (int a = 0; a < 4; ++a) {
        union { unsigned int i; float f; } lo, hi;
        lo.i = w[a] << 16;
        hi.i = w[a] & 0xFFFF0000u;
        f[a * 2]     = lo.f;
        f[a * 2 + 1] = hi.f;
    }
}

// ------------------------- fused fp32 -> bf16 cast -------------------------
__global__ __launch_bounds__(256) void cvt_all(const float* __restrict__ x,
                                               const float* __restrict__ wqkv,
                                               const float* __restrict__ wproj,
                                               unsigned short* __restrict__ xb,
                                               unsigned short* __restrict__ wqkvb,
                                               unsigned short* __restrict__ wprojb) {
    int i = blockIdx.x * 256 + threadIdx.x;
    const float* src;
    unsigned short* dst;
    if (i < 2097152)      { src = x;     dst = xb;                   }
    else if (i < 2883584) { src = wqkv;  dst = wqkvb;  i -= 2097152; }
    else                  { src = wproj; dst = wprojb; i -= 2883584; }
    float4 f = reinterpret_cast<const float4*>(src)[i];
    ushort4 u;
    u.x = f2b(f.x); u.y = f2b(f.y); u.z = f2b(f.z); u.w = f2b(f.w);
    reinterpret_cast<ushort4*>(dst)[i] = u;
}

// --------------------------- bf16 NT GEMM ----------------------------------
// C[m,n] = sum_k A[m,k]*B[n,k].  A: MxK rm, B: NxK rm (bf16 bits as ushort).
// Block tile BMxBN, BK=64.  4 waves 2x2; wave tile (BM/2)x(BN/2) as MIxNJ
// tiles of 32x32x16 MFMA.  LDS rows = 8 chunks of 16B; chunk c of row r at
// slot c^(r&7) -> conflict-free staging, swizzled reads.
// Grid is 1-D; XCD-chunked swizzle: wg -> tile = (wg&7)*(nwg/8) + wg/8,
// bn = tile % NBX (fastest), bm = tile / NBX.  With nwg/8 = 8*NBX each XCD
// owns 8 contiguous bm panels (2 MB of A) -> A re-reads become L2 hits.
__device__ __forceinline__ void store_c(float* C, long idx, float v)          { C[idx] = v; }
__device__ __forceinline__ void store_c(unsigned short* C, long idx, float v) { C[idx] = f2b(v); }

template <int BM, int BN, typename CT>
__global__ __launch_bounds__(256, 3) void gemm_bt(const unsigned short* __restrict__ A,
                                                  const unsigned short* __restrict__ B,
                                                  CT* __restrict__ C,
                                                  int M, int N, int K, int NBX) {
    constexpr int MI = BM / 64;                    // 32-row MFMA tiles per wave (M)
    constexpr int NJ = BN / 64;                    // 32-col MFMA tiles per wave (N)
    __shared__ __align__(16) unsigned short As[BM * 64];
    __shared__ __align__(16) unsigned short Bs[BN * 64];

    const int tid  = threadIdx.x;
    const int lane = tid & 63;
    const int wave = tid >> 6;

    // XCD-chunked bijective swizzle (gridDim.x % 8 == 0)
    const int wg   = blockIdx.x;
    const int cpx  = (int)gridDim.x >> 3;          // tiles per XCD chunk
    const int tile = (wg & 7) * cpx + (wg >> 3);
    const long bm  = tile / NBX;
    const long bn  = tile % NBX;

    const int wm   = (wave >> 1) * (BM / 2);
    const int wn   = (wave & 1) * (BN / 2);

    f32x16 acc[MI][NJ] = {};

    const unsigned short* Ab = A + bm * BM * (long)K;
    const unsigned short* Bb = B + bn * BN * (long)K;

    const int srow  = tid >> 3;                        // row within 32-row group
    const int sgcol = ((tid & 7) ^ (srow & 7)) << 3;   // swizzled SOURCE chunk

    for (int k0 = 0; k0 < K; k0 += 64) {
#pragma unroll
        for (int r = 0; r < BM / 32; ++r)
            __builtin_amdgcn_global_load_lds(
                (gbl_void*)(Ab + (long)(r * 32 + srow) * K + k0 + sgcol),
                (lds_void*)(As + (r * 256 + wave * 64) * 8), 16, 0, 0);
#pragma unroll
        for (int r = 0; r < BN / 32; ++r)
            __builtin_amdgcn_global_load_lds(
                (gbl_void*)(Bb + (long)(r * 32 + srow) * K + k0 + sgcol),
                (lds_void*)(Bs + (r * 256 + wave * 64) * 8), 16, 0, 0);
        __syncthreads();

        const int arow = lane & 31;
        const int kh   = lane >> 5;                    // k-half: k = kh*8 + j
#pragma unroll
        for (int kk = 0; kk < 4; ++kk) {               // 4 x K=16
            const int c  = kk * 2 + kh;                // logical chunk 0..7
            const int sw = (c ^ (lane & 7)) << 3;      // swizzled read offset
            bf16x8 af[MI], bfr[NJ];
#pragma unroll
            for (int i = 0; i < MI; ++i)
                af[i] = *reinterpret_cast<const bf16x8*>(As + (wm + i * 32 + arow) * 64 + sw);
#pragma unroll
            for (int j = 0; j < NJ; ++j)
                bfr[j] = *reinterpret_cast<const bf16x8*>(Bs + (wn + j * 32 + arow) * 64 + sw);
#pragma unroll
            for (int i = 0; i < MI; ++i)
#pragma unroll
                for (int j = 0; j < NJ; ++j)
                    acc[i][j] = __builtin_amdgcn_mfma_f32_32x32x16_bf16(af[i], bfr[j], acc[i][j], 0, 0, 0);
        }
        __syncthreads();
    }

    // C/D layout (verified m74/m101): col=lane&31, row=(r&3)+8*(r>>2)+4*(lane>>5)
    const long mbase = bm * BM + wm + ((lane >> 5) << 2);
    const long nbase = bn * BN + wn + (lane & 31);
#pragma unroll
    for (int i = 0; i < MI; ++i)
#pragma unroll
        for (int j = 0; j < NJ; ++j)
#pragma unroll
            for (int r = 0; r < 16; ++r) {
                const long row = mbase + i * 32 + (r & 3) + 8 * (r >> 2);
                store_c(C, row * (long)N + nbase + j * 32, acc[i][j][r]);
            }
}

// ------------------- per-row head attention + scatter ----------------------
// qkv row m=(b,t): q=e[0,1024), k=e[1024,2048), v=e[2048,3072); h=e/64%16.
// scores[i][j]=0.125*dot64(q_i,k_j); softmax over j; out[i][s]=sum_j a*v.
// Scatter: out[b,t,h,s] -> out3[b, h*128 + t/16, 64*(t%16)+s].
// rows[] is XOR chunk-swizzled: chunk c of 64-elem vector vi at c^(vi&7).
__global__ __launch_bounds__(256) void attn_rowlocal(const unsigned short* __restrict__ qkv,
                                                     unsigned short* __restrict__ out3) {
    __shared__ __align__(16) unsigned short rows[4 * 3072];  // 24 KB, swizzled
    __shared__ float attnS[4][16][17];                       // padded

    const int tid  = threadIdx.x;
    const int lane = tid & 63;
    const int wave = tid >> 6;
    const int m0   = blockIdx.x * 4;

    {   // cooperative load: LDS slot S gets global chunk (S&~7)|((S&7)^((S>>3)&7))
        const uint4* src = reinterpret_cast<const uint4*>(qkv + (long)m0 * 3072);
        uint4* dst = reinterpret_cast<uint4*>(rows);
#pragma unroll
        for (int c = 0; c < 6; ++c) {
            const int S  = c * 256 + tid;
            const int gs = (S & ~7) | ((S & 7) ^ ((S >> 3) & 7));
            dst[S] = src[gs];
        }
    }
    __syncthreads();

    const int m = m0 + wave;
    const int b = m >> 11;
    const int t = m & 2047;
    const unsigned short* rw = rows + wave * 3072;

    // scores: lane handles i = lane&15, j in [(lane>>4)*4, +4)
    const int i  = lane & 15;
    const int j0 = (lane >> 4) << 2;
    float sc[4] = {0.f, 0.f, 0.f, 0.f};
#pragma unroll
    for (int c8 = 0; c8 < 8; ++c8) {
        uint4 qu = *reinterpret_cast<const uint4*>(rw + i * 64 + ((c8 ^ (i & 7)) << 3));
        float qf[8];
        unpack8(qu, qf);
#pragma unroll
        for (int jj = 0; jj < 4; ++jj) {
            const int vi = 16 + j0 + jj;
            uint4 ku = *reinterpret_cast<const uint4*>(rw + vi * 64 + ((c8 ^ (vi & 7)) << 3));
            float kf[8];
            unpack8(ku, kf);
#pragma unroll
            for (int d = 0; d < 8; ++d) sc[jj] += qf[d] * kf[d];
        }
    }
#pragma unroll
    for (int jj = 0; jj < 4; ++jj) sc[jj] *= 0.125f;

    float mx = fmaxf(fmaxf(sc[0], sc[1]), fmaxf(sc[2], sc[3]));
    mx = fmaxf(mx, __shfl_xor(mx, 16));
    mx = fmaxf(mx, __shfl_xor(mx, 32));
    float sum = 0.f;
#pragma unroll
    for (int jj = 0; jj < 4; ++jj) { sc[jj] = __expf(sc[jj] - mx); sum += sc[jj]; }
    sum += __shfl_xor(sum, 16);
    sum += __shfl_xor(sum, 32);
    const float inv = 1.0f / sum;
#pragma unroll
    for (int jj = 0; jj < 4; ++jj) attnS[wave][i][j0 + jj] = sc[jj] * inv;
    __syncthreads();

    // out: lane handles head oi = lane>>2, s chunk s0 = (lane&3)*16
    const int oi = lane >> 2;
    const int s0 = (lane & 3) << 4;
    const int c0 = (lane & 3) << 1;
    float o[16];
#pragma unroll
    for (int ss = 0; ss < 16; ++ss) o[ss] = 0.f;
#pragma unroll
    for (int j = 0; j < 16; ++j) {
        const float a  = attnS[wave][oi][j];
        const int   vi = 32 + j;
        uint4 v0 = *reinterpret_cast<const uint4*>(rw + vi * 64 + (((c0)     ^ (vi & 7)) << 3));
        uint4 v1 = *reinterpret_cast<const uint4*>(rw + vi * 64 + (((c0 + 1) ^ (vi & 7)) << 3));
        float vf[16];
        unpack8(v0, vf);
        unpack8(v1, vf + 8);
#pragma unroll
        for (int ss = 0; ss < 16; ++ss) o[ss] += a * vf[ss];
    }

    uint4 r0, r1;
    r0.x = pack2(o[0],  o[1]);  r0.y = pack2(o[2],  o[3]);
    r0.z = pack2(o[4],  o[5]);  r0.w = pack2(o[6],  o[7]);
    r1.x = pack2(o[8],  o[9]);  r1.y = pack2(o[10], o[11]);
    r1.z = pack2(o[12], o[13]); r1.w = pack2(o[14], o[15]);

    const long base = (long)b * (2048 * 1024)
                    + (long)(oi * 128 + (t >> 4)) * 1024
                    + 64 * (t & 15) + s0;
    *reinterpret_cast<uint4*>(out3 + base)     = r0;
    *reinterpret_cast<uint4*>(out3 + base + 8) = r1;
}

// ------------------------------- launcher ----------------------------------
extern "C" void kernel_launch(void* const* d_in, const int* in_sizes, int n_in,
                              void* d_out, int out_size, void* d_ws, size_t ws_size,
                              hipStream_t stream) {
    const float* x     = (const float*)d_in[0];   // (4,2048,1024)
    const float* Wqkv  = (const float*)d_in[1];   // (3072,1024)
    const float* Wproj = (const float*)d_in[2];   // (1024,1024)
    float* out = (float*)d_out;                   // (4,2048,1024) fp32

    char* ws = (char*)d_ws;
    unsigned short* xb     = (unsigned short*)(ws);               // 16.0 MiB
    unsigned short* wqkvb  = (unsigned short*)(ws + 16777216);    //  6.0 MiB
    unsigned short* wprojb = (unsigned short*)(ws + 23068672);    //  2.0 MiB
    unsigned short* qkvb   = (unsigned short*)(ws + 25165824);    // 48.0 MiB
    unsigned short* out3b  = (unsigned short*)(ws + 75497472);    // 16.0 MiB

    // all three fp32->bf16 casts in one dispatch (3,145,728 float4s)
    cvt_all<<<dim3(12288), dim3(256), 0, stream>>>(x, Wqkv, Wproj, xb, wqkvb, wprojb);

    // qkv = x @ Wqkv^T : M=8192, N=3072, K=1024
    // 128x256 tiles, 768 blocks; XCD-chunked: each XCD owns 8 bm panels (2 MB A in L2)
    gemm_bt<128, 256, unsigned short><<<dim3(768), dim3(256), 0, stream>>>(
        xb, wqkvb, qkvb, 8192, 3072, 1024, 12);

    attn_rowlocal<<<dim3(2048), dim3(256), 0, stream>>>(qkvb, out3b);

    // out = out3 @ Wproj^T : M=8192, N=1024, K=1024
    // 128x128 tiles, 512 blocks; XCD-chunked: 8 bm panels + whole Wproj fit L2
    gemm_bt<128, 128, float><<<dim3(512), dim3(256), 0, stream>>>(
        out3b, wprojb, out, 8192, 1024, 1024, 8);
}